// Round 8
// baseline (21.386 us; speedup 1.0000x reference)
//
#include <hip/hip_runtime.h>
#include <math.h>

// ---------------------------------------------------------------------------
// QCNN forward, analytic form — SINGLE dispatch (no dependent-launch gaps).
//
// feat_w = sum_{p<=q} S_w[p,q] c^{16-p-q} s^{p+q} (Re S cos(d phi) - Im S sin(d phi))
// S_w[p,q] = sum_k z_k conj(G[k,p]) G[k,q],  G[:,p] = U*(indicator popc = p)
//
// 128 blocks x 576 threads. Each block redundantly:
//   1) 9 waves simulate the 9 indicator states in registers (DPP quad_perm for
//      masks 1,2; row_ror:8 for 8; ds_bpermute for 4,16,32; register bits 64,128;
//      Rz diagonal = zero comm).  [prims + gate code proven in R7]
//   2) dump to LDS, wave-parallel Hermitian reduce (wave w: pairs w, w+9, ...)
//      with butterfly + readlane finish -> stab[45].  [proven in R7]
//   3) eval 512 batch elements (tid < 512): 45-term polynomial + MLP.
//
// Qubit->mask (by comm traffic): q0=8 q1=1 q2=4 q3=64 q4=16 q5=128 q6=32 q7=2
// Z-signs for reduce: q3 -> k bit6 (= m&1); q7 -> k bit1 (= lane bit1).
// ---------------------------------------------------------------------------

#define PI_2F 1.57079632679489662f

__device__ __forceinline__ float2 cmad2(float2 A, float2 a, float2 B, float2 b) {
  return make_float2(A.x*a.x - A.y*a.y + B.x*b.x - B.y*b.y,
                     A.x*a.y + A.y*a.x + B.x*b.y + B.y*b.x);
}

template<int CTRL>
__device__ __forceinline__ float dpps(float v) {
  int r = __builtin_amdgcn_update_dpp(__float_as_int(v), __float_as_int(v),
                                      CTRL, 0xF, 0xF, false);
  return __int_as_float(r);
}

// partner value at lane^M — R7-proven prims only
template<int M>
__device__ __forceinline__ float lxs(float v, int lane) {
  if constexpr (M == 1)       return dpps<0xB1>(v);    // quad_perm(1,0,3,2)
  else if constexpr (M == 2)  return dpps<0x4E>(v);    // quad_perm(2,3,0,1)
  else if constexpr (M == 8)  return dpps<0x128>(v);   // row_ror:8
  else {
    int addr = (lane ^ M) << 2;
    return __int_as_float(__builtin_amdgcn_ds_bpermute(addr, __float_as_int(v)));
  }
}

template<int M>
__device__ __forceinline__ float2 lx2(float2 v, int lane) {
  return make_float2(lxs<M>(v.x, lane), lxs<M>(v.y, lane));
}

// ---- gates ------------------------------------------------------------------
template<int M>
__device__ __forceinline__ void rzd(float2 (&z)[4], int lane, float t) {
  float s, c; __sincosf(0.5f * t, &s, &c);
#pragma unroll
  for (int j = 0; j < 4; ++j) {
    bool hi;
    if constexpr (M < 64) hi = (lane & M) != 0;
    else                  hi = (j & (M >> 6)) != 0;
    float si = hi ? s : -s;
    z[j] = make_float2(c * z[j].x - si * z[j].y,
                       c * z[j].y + si * z[j].x);
  }
}

template<int M>
__device__ __forceinline__ void gate1r(float2 (&z)[4],
                                       float2 u00, float2 u01,
                                       float2 u10, float2 u11) {
  constexpr int jb = M >> 6;
#pragma unroll
  for (int j = 0; j < 4; ++j) {
    if ((j & jb) == 0) {
      float2 a = z[j], b = z[j + jb];
      z[j]      = cmad2(u00, a, u01, b);
      z[j + jb] = cmad2(u10, a, u11, b);
    }
  }
}

template<int M>
__device__ __forceinline__ void gate1c(float2 (&z)[4], int lane,
                                       float2 u00, float2 u01,
                                       float2 u10, float2 u11) {
  bool hi = (lane & M) != 0;
  float2 A = hi ? u11 : u00;
  float2 B = hi ? u10 : u01;
#pragma unroll
  for (int j = 0; j < 4; ++j) {
    float2 pv = lx2<M>(z[j], lane);
    z[j] = cmad2(A, z[j], B, pv);
  }
}

template<int M>
__device__ __forceinline__ void ryg(float2 (&z)[4], int lane, float t) {
  float s, c; __sincosf(0.5f * t, &s, &c);
  if constexpr (M < 64) {
    float sg = (lane & M) ? s : -s;
#pragma unroll
    for (int j = 0; j < 4; ++j) {
      float2 pv = lx2<M>(z[j], lane);
      z[j] = make_float2(c * z[j].x + sg * pv.x, c * z[j].y + sg * pv.y);
    }
  } else {
    gate1r<M>(z, make_float2(c, 0.f), make_float2(-s, 0.f),
                 make_float2(s, 0.f), make_float2(c, 0.f));
  }
}

template<int M>
__device__ __forceinline__ void u3g(float2 (&z)[4], int lane,
                                    float t, float p, float l) {
  float s, c;  __sincosf(0.5f * t, &s, &c);
  float sp, cp; __sincosf(p, &sp, &cp);
  float sl, cl; __sincosf(l, &sl, &cl);
  float spl, cpl; __sincosf(p + l, &spl, &cpl);
  float2 u00 = make_float2(c, 0.f),     u01 = make_float2(-cl*s, -sl*s);
  float2 u10 = make_float2(cp*s, sp*s), u11 = make_float2(cpl*c, spl*c);
  if constexpr (M < 64) gate1c<M>(z, lane, u00, u01, u10, u11);
  else                  gate1r<M>(z, u00, u01, u10, u11);
}

template<int MC, int MT>
__device__ __forceinline__ void cnotg(float2 (&z)[4], int lane) {
  if constexpr (MT < 64) {
#pragma unroll
    for (int j = 0; j < 4; ++j) {
      bool active = (MC < 64) || (((j << 6) & MC) != 0);
      if (active) {
        float2 pv = lx2<MT>(z[j], lane);
        bool sel = (MC >= 64) || ((lane & MC) != 0);
        z[j].x = sel ? pv.x : z[j].x;
        z[j].y = sel ? pv.y : z[j].y;
      }
    }
  } else {
    constexpr int jb = MT >> 6;
#pragma unroll
    for (int j = 0; j < 4; ++j) {
      if ((j & jb) == 0) {
        if (MC >= 64) {
          constexpr int cjb = MC >> 6;
          if ((j & cjb) != 0) { float2 t = z[j]; z[j] = z[j + jb]; z[j + jb] = t; }
        } else {
          bool sel = (lane & MC) != 0;
          float2 a = z[j], b = z[j + jb];
          z[j]      = make_float2(sel ? b.x : a.x, sel ? b.y : a.y);
          z[j + jb] = make_float2(sel ? a.x : b.x, sel ? a.y : b.y);
        }
      }
    }
  }
}

template<int MA, int MB, int MF>
__device__ __forceinline__ void blockg(float2 (&z)[4], int lane,
                                       float rzp, float ry1, float ry2) {
  rzd<MA>(z, lane, -PI_2F);
  cnotg<MA, MB>(z, lane);
  rzd<MB>(z, lane, rzp);
  ryg<MA>(z, lane, ry1);
  cnotg<MB, MA>(z, lane);
  ryg<MA>(z, lane, ry2);
  cnotg<MA, MB>(z, lane);
  rzd<MF>(z, lane, PI_2F);
}

__device__ __forceinline__ float fast_tanh(float x) {
  float e = __expf(2.f * x);
  return 1.f - 2.f / (e + 1.f);
}

// full-wave sum -> uniform scalar (butterfly within 32, readlane finish)
__device__ __forceinline__ float wsumu(float v, int lane) {
  v += lxs<1>(v, lane);
  v += lxs<2>(v, lane);
  v += lxs<4>(v, lane);
  v += lxs<8>(v, lane);
  v += lxs<16>(v, lane);
  float a = __int_as_float(__builtin_amdgcn_readlane(__float_as_int(v), 0));
  float b = __int_as_float(__builtin_amdgcn_readlane(__float_as_int(v), 32));
  return a + b;
}

// ---- fused kernel: per-block redundant sim + reduce, then eval -------------
__global__ __launch_bounds__(576)
void qcnn_all(const float* __restrict__ x, const float* __restrict__ rz,
              const float* __restrict__ ry, const float* __restrict__ u3,
              const float* __restrict__ W1, const float* __restrict__ b1,
              const float* __restrict__ W2, const float* __restrict__ b2,
              float* __restrict__ out, int B) {
  __shared__ float2 gl[9 * 256];
  __shared__ float4 stab[45];
  int tid = threadIdx.x;
  int p = tid >> 6, lane = tid & 63;

  // preload this thread's batch element early (hide HBM latency under sim)
  int i = blockIdx.x * 512 + tid;
  float2 tp = make_float2(0.f, 0.f);
  if (tid < 512) tp = reinterpret_cast<const float2*>(x)[i < B ? i : 0];

  // ---- sim: wave p owns indicator state popc==p, amplitudes in registers
  float2 z[4];
#pragma unroll
  for (int j = 0; j < 4; ++j) {
    int k = (j << 6) | lane;
    z[j] = make_float2(__popc(k) == p ? 1.f : 0.f, 0.f);
  }

  // masks: q0=8 q1=1 q2=4 q3=64 q4=16 q5=128 q6=32 q7=2
  blockg<1, 8, 8>(z, lane, rz[1],  ry[0],  ry[1]);      // block(1,0) fin=0
  blockg<64, 4, 4>(z, lane, rz[4],  ry[2],  ry[3]);     // block(3,2)
  blockg<128, 16, 16>(z, lane, rz[7],  ry[4],  ry[5]);  // block(5,4)
  blockg<2, 32, 32>(z, lane, rz[10], ry[6],  ry[7]);    // block(7,6)
  u3g<1>(z, lane, u3[0],  u3[1],  u3[2]);               // u3 q1
  u3g<64>(z, lane, u3[3],  u3[4],  u3[5]);              // u3 q3
  u3g<128>(z, lane, u3[6],  u3[7],  u3[8]);             // u3 q5
  u3g<2>(z, lane, u3[9],  u3[10], u3[11]);              // u3 q7
  blockg<64, 1, 1>(z, lane, rz[13], ry[8],  ry[9]);     // block(3,1) fin=1
  blockg<2, 128, 1>(z, lane, rz[16], ry[10], ry[11]);   // block(7,5) fin=1
  blockg<128, 64, 64>(z, lane, rz[19], ry[12], ry[13]); // block(5,3) fin=3
  u3g<64>(z, lane, u3[12], u3[13], u3[14]);             // u3 q3
  u3g<2>(z, lane, u3[15], u3[16], u3[17]);              // u3 q7

#pragma unroll
  for (int j = 0; j < 4; ++j)
    gl[p * 256 + (j << 6) + lane] = z[j];
  __syncthreads();

  // ---- reduce: wave w handles pairs w, w+9, ...; lane owns k = (m<<6)+lane
  float z7 = (lane & 2) ? -1.f : 1.f;
  for (int pr = p; pr < 45; pr += 9) {
    int pp = 0, base = 0, s = pr;
    while (s >= base + 9 - pp) { base += 9 - pp; ++pp; }
    int qq = pp + (s - base);

    float Ar = 0.f, Ai = 0.f, Br = 0.f, Bi = 0.f;
#pragma unroll
    for (int m = 0; m < 4; ++m) {
      float2 a = gl[pp * 256 + (m << 6) + lane];
      float2 b = gl[qq * 256 + (m << 6) + lane];
      float cr = a.x * b.x + a.y * b.y;     // conj(a)*b
      float ci = a.x * b.y - a.y * b.x;
      if (m & 1) { Br += cr; Bi += ci; } else { Ar += cr; Ai += ci; }
    }
    float v0 = wsumu(Ar - Br, lane);          // S3 re
    float v1 = wsumu(Ai - Bi, lane);          // S3 im
    float v2 = wsumu(z7 * (Ar + Br), lane);   // S7 re
    float v3 = wsumu(z7 * (Ai + Bi), lane);   // S7 im
    if (lane == 0) {
      float sc = (pp == qq) ? 1.f : 2.f;      // Hermitian fold
      stab[pr] = make_float4(sc * v0, sc * v1, sc * v2, sc * v3);
    }
  }
  __syncthreads();

  // ---- eval: 512 elements per block
  if (tid >= 512 || i >= B) return;

  float th = tp.x, ph = tp.y;
  float stt, ct;
  __sincosf(0.5f * th, &stt, &ct);
  float c1, s1;
  __sincosf(ph, &s1, &c1);

  float cpw[17], spw[17];
  cpw[0] = 1.f; spw[0] = 1.f;
#pragma unroll
  for (int k = 1; k < 17; ++k) { cpw[k] = cpw[k-1] * ct; spw[k] = spw[k-1] * stt; }

  float cd[9], sd[9];
  cd[0] = 1.f; sd[0] = 0.f;
  cd[1] = c1;  sd[1] = s1;
#pragma unroll
  for (int d = 2; d < 9; ++d) {
    cd[d] = cd[d-1] * c1 - sd[d-1] * s1;
    sd[d] = sd[d-1] * c1 + cd[d-1] * s1;
  }

  float f3 = 0.f, f7 = 0.f;
  int sidx = 0;
#pragma unroll
  for (int pp = 0; pp < 9; ++pp) {
#pragma unroll
    for (int qq = pp; qq < 9; ++qq) {
      float4 s4 = stab[sidx]; ++sidx;
      float w = cpw[16 - pp - qq] * spw[pp + qq];
      int d = qq - pp;
      f3 += w * (s4.x * cd[d] - s4.y * sd[d]);
      f7 += w * (s4.z * cd[d] - s4.w * sd[d]);
    }
  }

  float acc = b2[0];
#pragma unroll
  for (int j = 0; j < 10; ++j) {
    float h = fast_tanh(f3 * W1[j] + f7 * W1[10 + j] + b1[j]);
    acc += h * W2[j];
  }
  out[i] = 1.f / (1.f + __expf(-acc));
}

extern "C" void kernel_launch(void* const* d_in, const int* in_sizes, int n_in,
                              void* d_out, int out_size, void* d_ws, size_t ws_size,
                              hipStream_t stream) {
  const float* x  = (const float*)d_in[0];
  const float* rz = (const float*)d_in[1];
  const float* ry = (const float*)d_in[2];
  const float* u3 = (const float*)d_in[3];
  const float* W1 = (const float*)d_in[4];
  const float* b1 = (const float*)d_in[5];
  const float* W2 = (const float*)d_in[6];
  const float* b2 = (const float*)d_in[7];

  int B = in_sizes[0] / 2;                 // 65536
  int grid = (B + 511) / 512;              // 128 blocks x 512 evals
  qcnn_all<<<grid, 576, 0, stream>>>(x, rz, ry, u3, W1, b1, W2, b2,
                                     (float*)d_out, B);
}

// Round 9
// 19.564 us; speedup vs baseline: 1.0932x; 1.0932x over previous
//
#include <hip/hip_runtime.h>
#include <math.h>

// ---------------------------------------------------------------------------
// QCNN forward, analytic form — 2 dispatches, front-loaded params + trig.
//
// feat_w = sum_{p<=q} S_w[p,q] c^{16-p-q} s^{p+q} (Re S cos(d phi) - Im S sin(d phi))
// S_w[p,q] = sum_k z_k conj(G[k,p]) G[k,q],  G[:,p] = U*(indicator popc = p)
//
// K1 (9 blocks x 64): ALL parameter loads (wide s_load) and ALL sincos are
//   computed before the gate chain — the chain itself is pure FMA + DPP/
//   bpermute with zero loads/transcendentals on the critical path.
//   Prims (proven R7): DPP quad_perm (masks 1,2), row_ror:8 (8),
//   ds_bpermute (4,16,32), register bits (64,128), Rz diagonal.
// K2 (256 x 256): hoisted W/b loads, stage G->LDS, per-block redundant
//   Hermitian reduce (proven R7), then per-thread polynomial + MLP.
//
// Qubit->mask: q0=8 q1=1 q2=4 q3=64 q4=16 q5=128 q6=32 q7=2
// Z-signs for reduce: q3 -> k bit6 (= m&1); q7 -> k bit1 (= lane bit1).
// ---------------------------------------------------------------------------

#define QF 0.70710678118654752f   // cos(pi/4)

__device__ __forceinline__ float2 cmad2(float2 A, float2 a, float2 B, float2 b) {
  return make_float2(A.x*a.x - A.y*a.y + B.x*b.x - B.y*b.y,
                     A.x*a.y + A.y*a.x + B.x*b.y + B.y*b.x);
}

template<int CTRL>
__device__ __forceinline__ float dpps(float v) {
  int r = __builtin_amdgcn_update_dpp(__float_as_int(v), __float_as_int(v),
                                      CTRL, 0xF, 0xF, false);
  return __int_as_float(r);
}

// partner value at lane^M — R7-proven prims only
template<int M>
__device__ __forceinline__ float lxs(float v, int lane) {
  if constexpr (M == 1)       return dpps<0xB1>(v);    // quad_perm(1,0,3,2)
  else if constexpr (M == 2)  return dpps<0x4E>(v);    // quad_perm(2,3,0,1)
  else if constexpr (M == 8)  return dpps<0x128>(v);   // row_ror:8
  else {
    int addr = (lane ^ M) << 2;
    return __int_as_float(__builtin_amdgcn_ds_bpermute(addr, __float_as_int(v)));
  }
}

template<int M>
__device__ __forceinline__ float2 lx2(float2 v, int lane) {
  return make_float2(lxs<M>(v.x, lane), lxs<M>(v.y, lane));
}

// ---- gates (coefficient-passing versions: NO loads/trig inside) ------------
// diagonal Rz: coeffs (c, s) where full gate = diag(c - i s, c + i s)
template<int M>
__device__ __forceinline__ void rzdc(float2 (&z)[4], int lane, float c, float s) {
#pragma unroll
  for (int j = 0; j < 4; ++j) {
    bool hi;
    if constexpr (M < 64) hi = (lane & M) != 0;
    else                  hi = (j & (M >> 6)) != 0;
    float si = hi ? s : -s;
    z[j] = make_float2(c * z[j].x - si * z[j].y,
                       c * z[j].y + si * z[j].x);
  }
}

template<int M>
__device__ __forceinline__ void gate1r(float2 (&z)[4],
                                       float2 u00, float2 u01,
                                       float2 u10, float2 u11) {
  constexpr int jb = M >> 6;
#pragma unroll
  for (int j = 0; j < 4; ++j) {
    if ((j & jb) == 0) {
      float2 a = z[j], b = z[j + jb];
      z[j]      = cmad2(u00, a, u01, b);
      z[j + jb] = cmad2(u10, a, u11, b);
    }
  }
}

template<int M>
__device__ __forceinline__ void gate1c(float2 (&z)[4], int lane,
                                       float2 u00, float2 u01,
                                       float2 u10, float2 u11) {
  bool hi = (lane & M) != 0;
  float2 A = hi ? u11 : u00;
  float2 B = hi ? u10 : u01;
#pragma unroll
  for (int j = 0; j < 4; ++j) {
    float2 pv = lx2<M>(z[j], lane);
    z[j] = cmad2(A, z[j], B, pv);
  }
}

template<int M>
__device__ __forceinline__ void rygc(float2 (&z)[4], int lane, float c, float s) {
  if constexpr (M < 64) {
    float sg = (lane & M) ? s : -s;
#pragma unroll
    for (int j = 0; j < 4; ++j) {
      float2 pv = lx2<M>(z[j], lane);
      z[j] = make_float2(c * z[j].x + sg * pv.x, c * z[j].y + sg * pv.y);
    }
  } else {
    gate1r<M>(z, make_float2(c, 0.f), make_float2(-s, 0.f),
                 make_float2(s, 0.f), make_float2(c, 0.f));
  }
}

template<int M>
__device__ __forceinline__ void u3c(float2 (&z)[4], int lane,
                                    float2 u00, float2 u01,
                                    float2 u10, float2 u11) {
  if constexpr (M < 64) gate1c<M>(z, lane, u00, u01, u10, u11);
  else                  gate1r<M>(z, u00, u01, u10, u11);
}

template<int MC, int MT>
__device__ __forceinline__ void cnotg(float2 (&z)[4], int lane) {
  if constexpr (MT < 64) {
#pragma unroll
    for (int j = 0; j < 4; ++j) {
      bool active = (MC < 64) || (((j << 6) & MC) != 0);
      if (active) {
        float2 pv = lx2<MT>(z[j], lane);
        bool sel = (MC >= 64) || ((lane & MC) != 0);
        z[j].x = sel ? pv.x : z[j].x;
        z[j].y = sel ? pv.y : z[j].y;
      }
    }
  } else {
    constexpr int jb = MT >> 6;
#pragma unroll
    for (int j = 0; j < 4; ++j) {
      if ((j & jb) == 0) {
        if (MC >= 64) {
          constexpr int cjb = MC >> 6;
          if ((j & cjb) != 0) { float2 t = z[j]; z[j] = z[j + jb]; z[j + jb] = t; }
        } else {
          bool sel = (lane & MC) != 0;
          float2 a = z[j], b = z[j + jb];
          z[j]      = make_float2(sel ? b.x : a.x, sel ? b.y : a.y);
          z[j + jb] = make_float2(sel ? a.x : b.x, sel ? a.y : b.y);
        }
      }
    }
  }
}

// entangling block with precomputed coefficients
template<int MA, int MB, int MF>
__device__ __forceinline__ void blockgc(float2 (&z)[4], int lane,
                                        float2 zc, float2 y1, float2 y2) {
  rzdc<MA>(z, lane, QF, -QF);          // Rz(-pi/2)
  cnotg<MA, MB>(z, lane);
  rzdc<MB>(z, lane, zc.x, zc.y);       // Rz(rzp)
  rygc<MA>(z, lane, y1.x, y1.y);
  cnotg<MB, MA>(z, lane);
  rygc<MA>(z, lane, y2.x, y2.y);
  cnotg<MA, MB>(z, lane);
  rzdc<MF>(z, lane, QF, QF);           // Rz(+pi/2)
}

__device__ __forceinline__ float fast_tanh(float x) {
  float e = __expf(2.f * x);
  return 1.f - 2.f / (e + 1.f);
}

// full-wave sum -> uniform scalar (butterfly within 32, readlane finish)
__device__ __forceinline__ float wsumu(float v, int lane) {
  v += lxs<1>(v, lane);
  v += lxs<2>(v, lane);
  v += lxs<4>(v, lane);
  v += lxs<8>(v, lane);
  v += lxs<16>(v, lane);
  float a = __int_as_float(__builtin_amdgcn_readlane(__float_as_int(v), 0));
  float b = __int_as_float(__builtin_amdgcn_readlane(__float_as_int(v), 32));
  return a + b;
}

// ---- K1: simulate one indicator state per block (1 wave), write G ----------
__global__ __launch_bounds__(64)
void qcnn_sim(const float* __restrict__ rz, const float* __restrict__ ry,
              const float* __restrict__ u3, float2* __restrict__ G) {
  int lane = threadIdx.x;
  int p = blockIdx.x;

  // ---- 1) front-load ALL params (static indices -> wide scalar loads) ----
  float rzl[21], ryl[14], u3l[18];
#pragma unroll
  for (int k = 0; k < 21; ++k) rzl[k] = rz[k];
#pragma unroll
  for (int k = 0; k < 14; ++k) ryl[k] = ry[k];
#pragma unroll
  for (int k = 0; k < 18; ++k) u3l[k] = u3[k];

  // ---- 2) ALL trig up front (independent ops -> fully pipelined) ----
  float2 brz[7], by1[7], by2[7];       // (c, s) per entangling block
#pragma unroll
  for (int i = 0; i < 7; ++i) {
    __sincosf(0.5f * rzl[3*i+1], &brz[i].y, &brz[i].x);
    __sincosf(0.5f * ryl[2*i],   &by1[i].y, &by1[i].x);
    __sincosf(0.5f * ryl[2*i+1], &by2[i].y, &by2[i].x);
  }
  float2 U00[6], U01[6], U10[6], U11[6];
#pragma unroll
  for (int g = 0; g < 6; ++g) {
    float s, c;   __sincosf(0.5f * u3l[3*g], &s, &c);
    float sp, cp; __sincosf(u3l[3*g+1], &sp, &cp);
    float sl, cl; __sincosf(u3l[3*g+2], &sl, &cl);
    float spl, cpl; __sincosf(u3l[3*g+1] + u3l[3*g+2], &spl, &cpl);
    U00[g] = make_float2(c, 0.f);
    U01[g] = make_float2(-cl * s, -sl * s);
    U10[g] = make_float2(cp * s, sp * s);
    U11[g] = make_float2(cpl * c, spl * c);
  }

  // ---- 3) gate chain: pure FMA + DPP/bpermute, zero loads/trig ----
  float2 z[4];
#pragma unroll
  for (int j = 0; j < 4; ++j) {
    int k = (j << 6) | lane;
    z[j] = make_float2(__popc(k) == p ? 1.f : 0.f, 0.f);
  }

  // masks: q0=8 q1=1 q2=4 q3=64 q4=16 q5=128 q6=32 q7=2
  blockgc<1, 8, 8>(z, lane, brz[0], by1[0], by2[0]);      // block(1,0) fin=0
  blockgc<64, 4, 4>(z, lane, brz[1], by1[1], by2[1]);     // block(3,2)
  blockgc<128, 16, 16>(z, lane, brz[2], by1[2], by2[2]);  // block(5,4)
  blockgc<2, 32, 32>(z, lane, brz[3], by1[3], by2[3]);    // block(7,6)
  u3c<1>(z, lane, U00[0], U01[0], U10[0], U11[0]);        // u3 q1
  u3c<64>(z, lane, U00[1], U01[1], U10[1], U11[1]);       // u3 q3
  u3c<128>(z, lane, U00[2], U01[2], U10[2], U11[2]);      // u3 q5
  u3c<2>(z, lane, U00[3], U01[3], U10[3], U11[3]);        // u3 q7
  blockgc<64, 1, 1>(z, lane, brz[4], by1[4], by2[4]);     // block(3,1) fin=1
  blockgc<2, 128, 1>(z, lane, brz[5], by1[5], by2[5]);    // block(7,5) fin=1
  blockgc<128, 64, 64>(z, lane, brz[6], by1[6], by2[6]);  // block(5,3) fin=3
  u3c<64>(z, lane, U00[4], U01[4], U10[4], U11[4]);       // u3 q3
  u3c<2>(z, lane, U00[5], U01[5], U10[5], U11[5]);        // u3 q7

#pragma unroll
  for (int j = 0; j < 4; ++j)
    G[p * 256 + (j << 6) + lane] = z[j];
}

// ---- K2: stage G, redundant per-block reduce, then eval --------------------
__global__ __launch_bounds__(256)
void qcnn_eval(const float* __restrict__ x, const float2* __restrict__ G,
               const float* __restrict__ W1, const float* __restrict__ b1,
               const float* __restrict__ W2, const float* __restrict__ b2,
               float* __restrict__ out, int B) {
  __shared__ float2 gl[9 * 256];
  __shared__ float4 stab[45];
  int tid = threadIdx.x;
  int wid = tid >> 6, lane = tid & 63;

  // preload batch element + MLP weights early (hide latency under stage/reduce)
  int i = blockIdx.x * 256 + tid;
  float2 tp = reinterpret_cast<const float2*>(x)[i < B ? i : 0];

  float W1l[20], b1l[10], W2l[10], b2l;
#pragma unroll
  for (int k = 0; k < 20; ++k) W1l[k] = W1[k];
#pragma unroll
  for (int k = 0; k < 10; ++k) b1l[k] = b1[k];
#pragma unroll
  for (int k = 0; k < 10; ++k) W2l[k] = W2[k];
  b2l = b2[0];

  // stage G (coalesced)
#pragma unroll
  for (int w = 0; w < 9; ++w)
    gl[w * 256 + tid] = G[w * 256 + tid];

  // trig while the stage drains
  float th = tp.x, ph = tp.y;
  float stt, ct;
  __sincosf(0.5f * th, &stt, &ct);
  float c1, s1;
  __sincosf(ph, &s1, &c1);

  __syncthreads();

  // reduce: wave handles pairs wid, wid+4, ...; lane owns k = (m<<6)+lane.
  // z3 = k bit6 = m&1; z7 = k bit1 = lane bit1.
  float z7 = (lane & 2) ? -1.f : 1.f;
  for (int pr = wid; pr < 45; pr += 4) {
    int pp = 0, base = 0, s = pr;
    while (s >= base + 9 - pp) { base += 9 - pp; ++pp; }
    int qq = pp + (s - base);

    float Ar = 0.f, Ai = 0.f, Br = 0.f, Bi = 0.f;
#pragma unroll
    for (int m = 0; m < 4; ++m) {
      float2 a = gl[pp * 256 + (m << 6) + lane];
      float2 b = gl[qq * 256 + (m << 6) + lane];
      float cr = a.x * b.x + a.y * b.y;     // conj(a)*b
      float ci = a.x * b.y - a.y * b.x;
      if (m & 1) { Br += cr; Bi += ci; } else { Ar += cr; Ai += ci; }
    }
    float v0 = wsumu(Ar - Br, lane);          // S3 re
    float v1 = wsumu(Ai - Bi, lane);          // S3 im
    float v2 = wsumu(z7 * (Ar + Br), lane);   // S7 re
    float v3 = wsumu(z7 * (Ai + Bi), lane);   // S7 im
    if (lane == 0) {
      float sc = (pp == qq) ? 1.f : 2.f;      // Hermitian fold
      stab[pr] = make_float4(sc * v0, sc * v1, sc * v2, sc * v3);
    }
  }
  __syncthreads();

  if (i >= B) return;

  float cpw[17], spw[17];
  cpw[0] = 1.f; spw[0] = 1.f;
#pragma unroll
  for (int k = 1; k < 17; ++k) { cpw[k] = cpw[k-1] * ct; spw[k] = spw[k-1] * stt; }

  float cd[9], sd[9];
  cd[0] = 1.f; sd[0] = 0.f;
  cd[1] = c1;  sd[1] = s1;
#pragma unroll
  for (int d = 2; d < 9; ++d) {
    cd[d] = cd[d-1] * c1 - sd[d-1] * s1;
    sd[d] = sd[d-1] * c1 + cd[d-1] * s1;
  }

  float f3 = 0.f, f7 = 0.f;
  int sidx = 0;
#pragma unroll
  for (int pp = 0; pp < 9; ++pp) {
#pragma unroll
    for (int qq = pp; qq < 9; ++qq) {
      float4 s4 = stab[sidx]; ++sidx;
      float w = cpw[16 - pp - qq] * spw[pp + qq];
      int d = qq - pp;
      f3 += w * (s4.x * cd[d] - s4.y * sd[d]);
      f7 += w * (s4.z * cd[d] - s4.w * sd[d]);
    }
  }

  float acc = b2l;
#pragma unroll
  for (int j = 0; j < 10; ++j) {
    float h = fast_tanh(f3 * W1l[j] + f7 * W1l[10 + j] + b1l[j]);
    acc += h * W2l[j];
  }
  out[i] = 1.f / (1.f + __expf(-acc));
}

extern "C" void kernel_launch(void* const* d_in, const int* in_sizes, int n_in,
                              void* d_out, int out_size, void* d_ws, size_t ws_size,
                              hipStream_t stream) {
  const float* x  = (const float*)d_in[0];
  const float* rz = (const float*)d_in[1];
  const float* ry = (const float*)d_in[2];
  const float* u3 = (const float*)d_in[3];
  const float* W1 = (const float*)d_in[4];
  const float* b1 = (const float*)d_in[5];
  const float* W2 = (const float*)d_in[6];
  const float* b2 = (const float*)d_in[7];

  float2* G = (float2*)d_ws;               // 9*256*8 = 18432 B

  qcnn_sim<<<9, 64, 0, stream>>>(rz, ry, u3, G);

  int B = in_sizes[0] / 2;                 // 65536
  qcnn_eval<<<(B + 255) / 256, 256, 0, stream>>>(x, G, W1, b1, W2, b2,
                                                 (float*)d_out, B);
}